// Round 5
// baseline (167.379 us; speedup 1.0000x reference)
//
#include <hip/hip_runtime.h>

#define T_STEPS 200
#define IN_DIM 1086
#define KTILES 34              // ceil(1086/32)
#define M_TOTAL 51200          // 256*200

using f32x4v = __attribute__((ext_vector_type(4))) float;
using bf16x8 = __attribute__((ext_vector_type(8))) short;
using u32x4  = __attribute__((ext_vector_type(4))) unsigned int;
typedef unsigned uv2 __attribute__((ext_vector_type(2)));

#if __has_builtin(__builtin_amdgcn_permlane16_swap) && __has_builtin(__builtin_amdgcn_permlane32_swap)
#define HAVE_PERMLANE_SWAP 1
#else
#define HAVE_PERMLANE_SWAP 0
#endif

#if __has_builtin(__builtin_amdgcn_exp2f)
#define EXP2F(x) __builtin_amdgcn_exp2f(x)
#else
#define EXP2F(x) exp2f(x)
#endif

__device__ __forceinline__ float rl_f(float v, int lane) {
    return __uint_as_float((unsigned)__builtin_amdgcn_readlane((int)__float_as_uint(v), lane));
}

// ---------------------------------------------------------------------------
// prepack_w: W[64][1086] fp32 -> hi/lo bf16, fragment layout [kt][kg][64][8],
// zero-padded to K=1088. ~70k threads, negligible.
// ---------------------------------------------------------------------------
__global__ __launch_bounds__(256) void prepack_w(
    const float* __restrict__ W,
    unsigned short* __restrict__ Wh, unsigned short* __restrict__ Wl)
{
    int idx = blockIdx.x * 256 + threadIdx.x;
    if (idx >= KTILES * 4 * 64 * 8) return;
    int j = idx & 7;
    int n = (idx >> 3) & 63;
    int k = (idx >> 9) * 8 + j;
    float v = (k < IN_DIM) ? W[n * IN_DIM + k] : 0.0f;
    unsigned u = __float_as_uint(v);
    unsigned hi = u & 0xffff0000u;
    float lo = v - __uint_as_float(hi);
    Wh[idx] = (unsigned short)(u >> 16);
    Wl[idx] = (unsigned short)(__float_as_uint(lo) >> 16);
}

// ---------------------------------------------------------------------------
// pre0_gemm_v2: x @ W_ih0^T + b0, one wave per 32 rows, register-resident,
// branch-free main loop with explicit 2-buffer software pipeline so ~12KB/wave
// of loads stay in flight (MLP fix for the 886GB/s..1.9TB/s plateau).
// ---------------------------------------------------------------------------
__device__ __forceinline__ void cvt_hilo(const float (&a)[8], bf16x8& hv, bf16x8& lv) {
    union { u32x4 u; bf16x8 v; } H, L;
    #pragma unroll
    for (int p = 0; p < 4; ++p) {
        float a0 = a[2 * p], a1 = a[2 * p + 1];
        unsigned u0 = __float_as_uint(a0), u1 = __float_as_uint(a1);
        unsigned h0 = u0 & 0xffff0000u, h1 = u1 & 0xffff0000u;
        H.u[p] = (u0 >> 16) | h1;
        float l0 = a0 - __uint_as_float(h0);
        float l1 = a1 - __uint_as_float(h1);
        L.u[p] = (__float_as_uint(l0) >> 16) | (__float_as_uint(l1) & 0xffff0000u);
    }
    hv = H.v; lv = L.v;
}

__device__ __forceinline__ void load_a(
    const float* __restrict__ xr0, const float* __restrict__ xr1, int kb,
    float (&A0)[8], float (&A1)[8])
{
    #pragma unroll
    for (int q = 0; q < 4; ++q) {
        float2 t0 = *(const float2*)(xr0 + kb + 2 * q);
        float2 t1 = *(const float2*)(xr1 + kb + 2 * q);
        A0[2 * q] = t0.x; A0[2 * q + 1] = t0.y;
        A1[2 * q] = t1.x; A1[2 * q + 1] = t1.y;
    }
}

__device__ __forceinline__ void load_a_tail(
    const float* __restrict__ xr0, const float* __restrict__ xr1, int kb,
    float (&A0)[8], float (&A1)[8])
{
    #pragma unroll
    for (int j = 0; j < 8; ++j) {
        int k = kb + j;
        A0[j] = (k < IN_DIM) ? xr0[k] : 0.0f;
        A1[j] = (k < IN_DIM) ? xr1[k] : 0.0f;
    }
}

__device__ __forceinline__ void load_b(
    const unsigned short* __restrict__ Wh, const unsigned short* __restrict__ Wl,
    int kt, int kg, int fr, bf16x8 (&BH)[4], bf16x8 (&BL)[4])
{
    const long bbase = (long)(kt * 4 + kg) * 64 * 8;
    #pragma unroll
    for (int nf = 0; nf < 4; ++nf) {
        BH[nf] = *(const bf16x8*)(Wh + bbase + (nf * 16 + fr) * 8);
        BL[nf] = *(const bf16x8*)(Wl + bbase + (nf * 16 + fr) * 8);
    }
}

__device__ __forceinline__ void proc(
    const float (&A0)[8], const float (&A1)[8],
    const bf16x8 (&BH)[4], const bf16x8 (&BL)[4], f32x4v (&acc)[2][4])
{
    bf16x8 ah0, al0, ah1, al1;
    cvt_hilo(A0, ah0, al0);
    cvt_hilo(A1, ah1, al1);
    #pragma unroll
    for (int nf = 0; nf < 4; ++nf) {
        acc[0][nf] = __builtin_amdgcn_mfma_f32_16x16x32_bf16(ah0, BH[nf], acc[0][nf], 0, 0, 0);
        acc[0][nf] = __builtin_amdgcn_mfma_f32_16x16x32_bf16(al0, BH[nf], acc[0][nf], 0, 0, 0);
        acc[0][nf] = __builtin_amdgcn_mfma_f32_16x16x32_bf16(ah0, BL[nf], acc[0][nf], 0, 0, 0);
        acc[1][nf] = __builtin_amdgcn_mfma_f32_16x16x32_bf16(ah1, BH[nf], acc[1][nf], 0, 0, 0);
        acc[1][nf] = __builtin_amdgcn_mfma_f32_16x16x32_bf16(al1, BH[nf], acc[1][nf], 0, 0, 0);
        acc[1][nf] = __builtin_amdgcn_mfma_f32_16x16x32_bf16(ah1, BL[nf], acc[1][nf], 0, 0, 0);
    }
}

__global__ __launch_bounds__(64) void pre0_gemm_v2(
    const float* __restrict__ X,
    const unsigned short* __restrict__ Wh, const unsigned short* __restrict__ Wl,
    const float* __restrict__ bias, float* __restrict__ out)
{
    const int lane = threadIdx.x;
    const int fr = lane & 15;
    const int kg = lane >> 4;
    const long m0 = (long)blockIdx.x * 32;

    const float* xr0 = X + (m0 + fr) * (long)IN_DIM;
    const float* xr1 = X + (m0 + 16 + fr) * (long)IN_DIM;

    f32x4v acc[2][4];
    #pragma unroll
    for (int mf = 0; mf < 2; ++mf)
        #pragma unroll
        for (int nf = 0; nf < 4; ++nf)
            #pragma unroll
            for (int r = 0; r < 4; ++r) acc[mf][nf][r] = 0.0f;

    // named double buffers (static indexing only)
    float A0a[8], A1a[8], A0b[8], A1b[8];
    bf16x8 BHa[4], BLa[4], BHb[4], BLb[4];

    // prologue: tile 0 -> buf a
    load_a(xr0, xr1, 0 * 32 + kg * 8, A0a, A1a);
    load_b(Wh, Wl, 0, kg, fr, BHa, BLa);

    // main loop: tiles 0..31, branch-free; prefetch kt+1 / kt+2 before use
    for (int kt = 0; kt < 32; kt += 2) {
        load_a(xr0, xr1, (kt + 1) * 32 + kg * 8, A0b, A1b);
        load_b(Wh, Wl, kt + 1, kg, fr, BHb, BLb);
        proc(A0a, A1a, BHa, BLa, acc);
        load_a(xr0, xr1, (kt + 2) * 32 + kg * 8, A0a, A1a);
        load_b(Wh, Wl, kt + 2, kg, fr, BHa, BLa);
        proc(A0b, A1b, BHb, BLb, acc);
    }
    // epilogue: buf a holds tile 32; prefetch masked tile 33, then drain both
    load_a_tail(xr0, xr1, 33 * 32 + kg * 8, A0b, A1b);
    load_b(Wh, Wl, 33, kg, fr, BHb, BLb);
    proc(A0a, A1a, BHa, BLa, acc);
    proc(A0b, A1b, BHb, BLb, acc);

    // epilogue: +bias, fp32 store. C/D map: col=lane&15, row=(lane>>4)*4+r
    float bvv[4];
    #pragma unroll
    for (int nf = 0; nf < 4; ++nf) bvv[nf] = bias[nf * 16 + fr];
    #pragma unroll
    for (int mf = 0; mf < 2; ++mf)
        #pragma unroll
        for (int nf = 0; nf < 4; ++nf)
            #pragma unroll
            for (int r = 0; r < 4; ++r) {
                long row = m0 + mf * 16 + kg * 4 + r;
                out[row * 64 + nf * 16 + fr] = acc[mf][nf][r] + bvv[nf];
            }
}

// ---------------------------------------------------------------------------
// mega_scan: 4-wave layer pipeline (unchanged — ~45us).
// ---------------------------------------------------------------------------
__global__ __launch_bounds__(256) void mega_scan(
    const float* __restrict__ pre0, const float* __restrict__ whh0,
    const float* __restrict__ wih1, const float* __restrict__ whh1, const float* __restrict__ b1,
    const float* __restrict__ wih2, const float* __restrict__ whh2, const float* __restrict__ b2,
    const float* __restrict__ wih3, const float* __restrict__ whh3, const float* __restrict__ b3,
    const float* __restrict__ w_fc1, const float* __restrict__ b_fc1,
    const float* __restrict__ w_fc2, const float* __restrict__ b_fc2,
    float* __restrict__ out)
{
    __shared__ float buf[3][T_STEPS][16];

    const int b    = blockIdx.x;
    const int tid  = threadIdx.x;
    const int g    = tid & 63;
    const int wv   = tid >> 6;

    bool sel16 = false, sel32 = false;
#if HAVE_PERMLANE_SWAP
    {
        uv2 q16 = __builtin_amdgcn_permlane16_swap((unsigned)g, (unsigned)g, false, false);
        sel16 = (__builtin_amdgcn_readfirstlane((int)q16[1]) == 16);
        uv2 q32 = __builtin_amdgcn_permlane32_swap((unsigned)g, (unsigned)g, false, false);
        sel32 = (__builtin_amdgcn_readfirstlane((int)q32[1]) == 32);
    }
#endif

    const float* wih = nullptr; const float* whh; const float* bias = nullptr;
    if      (wv == 0) { whh = whh0; }
    else if (wv == 1) { wih = wih1; whh = whh1; bias = b1; }
    else if (wv == 2) { wih = wih2; whh = whh2; bias = b2; }
    else              { wih = wih3; whh = whh3; bias = b3; }

    float whh_r[16];
    #pragma unroll
    for (int q = 0; q < 4; ++q)
        *(float4*)&whh_r[q * 4] = *(const float4*)&whh[g * 16 + q * 4];
    float wih_r[16]; float bg = 0.0f;
    if (wv) {
        #pragma unroll
        for (int q = 0; q < 4; ++q)
            *(float4*)&wih_r[q * 4] = *(const float4*)&wih[g * 16 + q * 4];
        bg = bias[g];
    }

    const float* pb = pre0 + (long)b * T_STEPS * 64 + g;
    float pc = 0.0f, p1 = 0.0f, p2 = 0.0f;
    if (wv == 0) { pc = pb[0]; p1 = pb[64]; p2 = pb[128]; }

    float hs[16];
    #pragma unroll
    for (int k = 0; k < 16; ++k) hs[k] = 0.0f;
    float c = 0.0f;

    const int q4 = g >> 4;
    const float escale = (q4 == 2) ? -2.8853900817779268f : -1.4426950408889634f;
    const float am = (q4 == 2) ? 2.0f : 1.0f;
    const float aa = (q4 == 2) ? -1.0f : 0.0f;

    for (int tau = 0; tau < T_STEPS + 3; ++tau) {
        __syncthreads();
        const int t = tau - wv;
        if (t >= 0 && t < T_STEPS) {
            float xr[16];
            if (wv) {
                #pragma unroll
                for (int q = 0; q < 4; ++q)
                    *(float4*)&xr[q * 4] = *(const float4*)&buf[wv - 1][t][q * 4];
            }
            float r0 = fmaf(whh_r[0], hs[0], wv ? bg : pc);
            float r1 = whh_r[1] * hs[1];
            float r2 = whh_r[2] * hs[2];
            float r3 = whh_r[3] * hs[3];
            #pragma unroll
            for (int k = 4; k < 16; k += 4) {
                r0 = fmaf(whh_r[k + 0], hs[k + 0], r0);
                r1 = fmaf(whh_r[k + 1], hs[k + 1], r1);
                r2 = fmaf(whh_r[k + 2], hs[k + 2], r2);
                r3 = fmaf(whh_r[k + 3], hs[k + 3], r3);
            }
            float acc = (r0 + r1) + (r2 + r3);
            if (wv) {
                float p0 = wih_r[0] * xr[0];
                float q1 = wih_r[1] * xr[1];
                float q2 = wih_r[2] * xr[2];
                float q3 = wih_r[3] * xr[3];
                #pragma unroll
                for (int k = 4; k < 16; k += 4) {
                    p0 = fmaf(wih_r[k + 0], xr[k + 0], p0);
                    q1 = fmaf(wih_r[k + 1], xr[k + 1], q1);
                    q2 = fmaf(wih_r[k + 2], xr[k + 2], q2);
                    q3 = fmaf(wih_r[k + 3], xr[k + 3], q3);
                }
                acc += (p0 + q1) + (q2 + q3);
            }
            float e = EXP2F(escale * acc);
            float s = __builtin_amdgcn_rcpf(1.0f + e);
            float a = fmaf(am, s, aa);
#if HAVE_PERMLANE_SWAP
            unsigned au = __float_as_uint(a);
            uv2 r16 = __builtin_amdgcn_permlane16_swap(au, au, false, false);
            uv2 r32 = __builtin_amdgcn_permlane32_swap(au, au, false, false);
            unsigned fvu = sel16 ? r16[1] : r16[0];
            unsigned gvu = sel32 ? r32[1] : r32[0];
            uv2 r48 = __builtin_amdgcn_permlane16_swap(gvu, gvu, false, false);
            unsigned ovu = sel16 ? r48[1] : r48[0];
            float fv = __uint_as_float(fvu);
            float gv = __uint_as_float(gvu);
            float ov = __uint_as_float(ovu);
#else
            float fv = __shfl_xor(a, 16, 64);
            float gv = __shfl_xor(a, 32, 64);
            float ov = __shfl_xor(a, 48, 64);
#endif
            c = fmaf(fv, c, a * gv);
            float e2 = EXP2F(-2.8853900817779268f * c);
            float s2 = __builtin_amdgcn_rcpf(1.0f + e2);
            float hn = fmaf(ov + ov, s2, -ov);
            if (wv < 3 && g < 16) buf[wv][t][g] = hn;
            #pragma unroll
            for (int k = 0; k < 16; ++k) hs[k] = rl_f(hn, k);
            if (wv == 0) {
                pc = p1; p1 = p2;
                int tn = t + 3; tn = tn < T_STEPS ? tn : T_STEPS - 1;
                p2 = pb[(long)tn * 64];
            }
        }
    }

    if (wv == 3 && g < 16) {
        float a1 = b_fc1[g];
        #pragma unroll
        for (int k = 0; k < 16; ++k) a1 = fmaf(w_fc1[g * 16 + k], hs[k], a1);
        a1 = fmaxf(a1, 0.0f);
        float h1[16];
        #pragma unroll
        for (int k = 0; k < 16; ++k) h1[k] = rl_f(a1, k);
        float lg = -3.0e38f;
        if (g < 15) {
            lg = b_fc2[g];
            #pragma unroll
            for (int k = 0; k < 16; ++k) lg = fmaf(w_fc2[g * 16 + k], h1[k], lg);
        }
        float mx = lg;
        #pragma unroll
        for (int d = 8; d >= 1; d >>= 1) mx = fmaxf(mx, __shfl_xor(mx, d, 16));
        float ev = (g < 15) ? EXP2F(1.4426950408889634f * (lg - mx)) : 0.0f;
        float sm = ev;
        #pragma unroll
        for (int d = 8; d >= 1; d >>= 1) sm += __shfl_xor(sm, d, 16);
        if (g < 15) out[b * 15 + g] = ev * __builtin_amdgcn_rcpf(sm);
    }
}

extern "C" void kernel_launch(void* const* d_in, const int* in_sizes, int n_in,
                              void* d_out, int out_size, void* d_ws, size_t ws_size,
                              hipStream_t stream) {
    const float* x    = (const float*)d_in[0];
    const float* wih0 = (const float*)d_in[1];
    const float* whh0 = (const float*)d_in[2];
    const float* b0   = (const float*)d_in[3];
    const float* wih1 = (const float*)d_in[4];
    const float* whh1 = (const float*)d_in[5];
    const float* b1   = (const float*)d_in[6];
    const float* wih2 = (const float*)d_in[7];
    const float* whh2 = (const float*)d_in[8];
    const float* b2   = (const float*)d_in[9];
    const float* wih3 = (const float*)d_in[10];
    const float* whh3 = (const float*)d_in[11];
    const float* b3   = (const float*)d_in[12];
    const float* wfc1 = (const float*)d_in[13];
    const float* bfc1 = (const float*)d_in[14];
    const float* wfc2 = (const float*)d_in[15];
    const float* bfc2 = (const float*)d_in[16];

    float* pre0 = (float*)d_ws;                                       // 13,107,200 B
    unsigned short* Wh = (unsigned short*)((char*)d_ws + 13107200);   // 139,264 B
    unsigned short* Wl = (unsigned short*)((char*)d_ws + 13107200 + 139264);

    prepack_w<<<dim3((KTILES * 4 * 64 * 8 + 255) / 256), dim3(256), 0, stream>>>(wih0, Wh, Wl);
    pre0_gemm_v2<<<dim3(M_TOTAL / 32), dim3(64), 0, stream>>>(x, Wh, Wl, b0, pre0);
    mega_scan<<<dim3(256), dim3(256), 0, stream>>>(pre0, whh0,
        wih1, whh1, b1, wih2, whh2, b2, wih3, whh3, b3,
        wfc1, bfc1, wfc2, bfc2, (float*)d_out);
}

// Round 6
// 162.518 us; speedup vs baseline: 1.0299x; 1.0299x over previous
//
#include <hip/hip_runtime.h>

#define T_STEPS 200
#define IN_DIM 1086
#define KTILES 34              // ceil(1086/32)
#define M_TOTAL 51200          // 256*200

using f32x4v  = __attribute__((ext_vector_type(4))) float;
using bf16x8  = __attribute__((ext_vector_type(8))) short;
using u32x4   = __attribute__((ext_vector_type(4))) unsigned int;
using ushort8 = __attribute__((ext_vector_type(8))) unsigned short;
typedef unsigned uv2 __attribute__((ext_vector_type(2)));

#if __has_builtin(__builtin_amdgcn_permlane16_swap) && __has_builtin(__builtin_amdgcn_permlane32_swap)
#define HAVE_PERMLANE_SWAP 1
#else
#define HAVE_PERMLANE_SWAP 0
#endif

#if __has_builtin(__builtin_amdgcn_exp2f)
#define EXP2F(x) __builtin_amdgcn_exp2f(x)
#else
#define EXP2F(x) exp2f(x)
#endif

__device__ __forceinline__ float rl_f(float v, int lane) {
    return __uint_as_float((unsigned)__builtin_amdgcn_readlane((int)__float_as_uint(v), lane));
}

// ---------------------------------------------------------------------------
// prepack_w: W[64][1086] fp32 -> hi/lo bf16, fragment layout [kt][kg][64][8],
// zero-padded to K=1088. Per kt: 2048 shorts contiguous (4KB).
// ---------------------------------------------------------------------------
__global__ __launch_bounds__(256) void prepack_w(
    const float* __restrict__ W,
    unsigned short* __restrict__ Wh, unsigned short* __restrict__ Wl)
{
    int idx = blockIdx.x * 256 + threadIdx.x;
    if (idx >= KTILES * 4 * 64 * 8) return;
    int j = idx & 7;
    int n = (idx >> 3) & 63;
    int k = (idx >> 9) * 8 + j;
    float v = (k < IN_DIM) ? W[n * IN_DIM + k] : 0.0f;
    unsigned u = __float_as_uint(v);
    unsigned hi = u & 0xffff0000u;
    float lo = v - __uint_as_float(hi);
    Wh[idx] = (unsigned short)(u >> 16);
    Wl[idx] = (unsigned short)(__float_as_uint(lo) >> 16);
}

__device__ __forceinline__ void cvt_hilo(const float (&a)[8], bf16x8& hv, bf16x8& lv) {
    union { u32x4 u; bf16x8 v; } H, L;
    #pragma unroll
    for (int p = 0; p < 4; ++p) {
        float a0 = a[2 * p], a1 = a[2 * p + 1];
        unsigned u0 = __float_as_uint(a0), u1 = __float_as_uint(a1);
        unsigned h0 = u0 & 0xffff0000u, h1 = u1 & 0xffff0000u;
        H.u[p] = (u0 >> 16) | h1;
        float l0 = a0 - __uint_as_float(h0);
        float l1 = a1 - __uint_as_float(h1);
        L.u[p] = (__float_as_uint(l0) >> 16) | (__float_as_uint(l1) & 0xffff0000u);
    }
    hv = H.v; lv = L.v;
}

// ---------------------------------------------------------------------------
// pre0_gemm_v3: m97-style 2-barrier LDS-staged K-loop. BM=64, BK=32, 4 waves.
// A staged with coalesced 8B loads (consecutive lanes -> consecutive bytes in
// a row) + XOR-swizzled ds_write_b64 (T2: chunk ^= row&7 within each row's
// 128B, so strided frag b128 reads are minimum-aliasing). B staged from the
// prepacked layout with 16B load + ds_write_b128 (linear, conflict-free).
// Cross-block phase overlap hides the per-tile latency (3+ blocks/CU).
// ---------------------------------------------------------------------------
__global__ __launch_bounds__(256) void pre0_gemm_v3(
    const float* __restrict__ X,
    const unsigned short* __restrict__ Wh, const unsigned short* __restrict__ Wl,
    const float* __restrict__ bias, float* __restrict__ out)
{
    __shared__ float As[64 * 32];           // 8KB, swizzled X k-tile
    __shared__ unsigned short BsH[2048];    // 4KB, [kg][64][8]
    __shared__ unsigned short BsL[2048];    // 4KB

    const int tid  = threadIdx.x;
    const int lane = tid & 63;
    const int wv   = tid >> 6;
    const int fr   = lane & 15;
    const int kg   = lane >> 4;
    const long m0  = (long)blockIdx.x * 64;

    // ---- A staging geometry: thread covers floats [(tid&15)*2, +2) of rows
    // row0, row0+16, row0+32, row0+48 within the 64x32 tile.
    const int row0 = tid >> 4;                                   // 0..15
    const int cch  = (tid >> 1) & 7;                             // logical 16B chunk
    const int half = tid & 1;
    const int ldsA0 = row0 * 128 + ((cch ^ (row0 & 7)) << 4) + half * 8;  // bytes
    const bool tailskip = (tid & 15) == 15;                      // k=1086,1087 pad
    const float* xsrc = X + (m0 + row0) * (long)IN_DIM + (tid & 15) * 2;
    char* aB = (char*)As;

    f32x4v acc[4];
    #pragma unroll
    for (int nf = 0; nf < 4; ++nf)
        #pragma unroll
        for (int r = 0; r < 4; ++r) acc[nf][r] = 0.0f;

    for (int kt = 0; kt < KTILES; ++kt) {
        const bool tail = (kt == KTILES - 1);
        __syncthreads();                       // prev compute done, LDS reusable

        // ---- stage: issue all global loads first, then LDS writes
        float2 av[4];
        #pragma unroll
        for (int i = 0; i < 4; ++i) {
            float2 v;
            if (tail && tailskip) { v.x = 0.0f; v.y = 0.0f; }
            else v = *(const float2*)(xsrc + (long)i * 16 * IN_DIM + kt * 32);
            av[i] = v;
        }
        ushort8 bhv = *(const ushort8*)(Wh + kt * 2048 + tid * 8);
        ushort8 blv = *(const ushort8*)(Wl + kt * 2048 + tid * 8);
        #pragma unroll
        for (int i = 0; i < 4; ++i)
            *(float2*)(aB + ldsA0 + i * 2048) = av[i];
        *(ushort8*)(BsH + tid * 8) = bhv;
        *(ushort8*)(BsL + tid * 8) = blv;
        __syncthreads();                       // stage visible (vmcnt+lgkm drain)

        // ---- compute: frags from LDS, hi/lo cvt, 12 MFMA per wave
        const int r = wv * 16 + fr;
        const int s = fr & 7;
        const float* pa1 = As + r * 32 + ((((2 * kg)    ) ^ s) << 2);
        const float* pa2 = As + r * 32 + ((((2 * kg) | 1) ^ s) << 2);
        float a[8];
        *(f32x4v*)&a[0] = *(const f32x4v*)pa1;
        *(f32x4v*)&a[4] = *(const f32x4v*)pa2;
        bf16x8 ah, al;
        cvt_hilo(a, ah, al);
        bf16x8 bh[4], bl[4];
        #pragma unroll
        for (int nf = 0; nf < 4; ++nf) {
            bh[nf] = *(const bf16x8*)(BsH + (kg * 64 + nf * 16 + fr) * 8);
            bl[nf] = *(const bf16x8*)(BsL + (kg * 64 + nf * 16 + fr) * 8);
        }
        #pragma unroll
        for (int nf = 0; nf < 4; ++nf) {
            acc[nf] = __builtin_amdgcn_mfma_f32_16x16x32_bf16(ah, bh[nf], acc[nf], 0, 0, 0);
            acc[nf] = __builtin_amdgcn_mfma_f32_16x16x32_bf16(al, bh[nf], acc[nf], 0, 0, 0);
            acc[nf] = __builtin_amdgcn_mfma_f32_16x16x32_bf16(ah, bl[nf], acc[nf], 0, 0, 0);
        }
    }

    // ---- epilogue: +bias, fp32 store. C/D map: col=lane&15, row=(lane>>4)*4+r
    float bvv[4];
    #pragma unroll
    for (int nf = 0; nf < 4; ++nf) bvv[nf] = bias[nf * 16 + fr];
    #pragma unroll
    for (int nf = 0; nf < 4; ++nf)
        #pragma unroll
        for (int rr = 0; rr < 4; ++rr) {
            long row = m0 + wv * 16 + kg * 4 + rr;
            out[row * 64 + nf * 16 + fr] = acc[nf][rr] + bvv[nf];
        }
}

// ---------------------------------------------------------------------------
// mega_scan: 4-wave layer pipeline (unchanged — ~45us).
// ---------------------------------------------------------------------------
__global__ __launch_bounds__(256) void mega_scan(
    const float* __restrict__ pre0, const float* __restrict__ whh0,
    const float* __restrict__ wih1, const float* __restrict__ whh1, const float* __restrict__ b1,
    const float* __restrict__ wih2, const float* __restrict__ whh2, const float* __restrict__ b2,
    const float* __restrict__ wih3, const float* __restrict__ whh3, const float* __restrict__ b3,
    const float* __restrict__ w_fc1, const float* __restrict__ b_fc1,
    const float* __restrict__ w_fc2, const float* __restrict__ b_fc2,
    float* __restrict__ out)
{
    __shared__ float buf[3][T_STEPS][16];

    const int b    = blockIdx.x;
    const int tid  = threadIdx.x;
    const int g    = tid & 63;
    const int wv   = tid >> 6;

    bool sel16 = false, sel32 = false;
#if HAVE_PERMLANE_SWAP
    {
        uv2 q16 = __builtin_amdgcn_permlane16_swap((unsigned)g, (unsigned)g, false, false);
        sel16 = (__builtin_amdgcn_readfirstlane((int)q16[1]) == 16);
        uv2 q32 = __builtin_amdgcn_permlane32_swap((unsigned)g, (unsigned)g, false, false);
        sel32 = (__builtin_amdgcn_readfirstlane((int)q32[1]) == 32);
    }
#endif

    const float* wih = nullptr; const float* whh; const float* bias = nullptr;
    if      (wv == 0) { whh = whh0; }
    else if (wv == 1) { wih = wih1; whh = whh1; bias = b1; }
    else if (wv == 2) { wih = wih2; whh = whh2; bias = b2; }
    else              { wih = wih3; whh = whh3; bias = b3; }

    float whh_r[16];
    #pragma unroll
    for (int q = 0; q < 4; ++q)
        *(float4*)&whh_r[q * 4] = *(const float4*)&whh[g * 16 + q * 4];
    float wih_r[16]; float bg = 0.0f;
    if (wv) {
        #pragma unroll
        for (int q = 0; q < 4; ++q)
            *(float4*)&wih_r[q * 4] = *(const float4*)&wih[g * 16 + q * 4];
        bg = bias[g];
    }

    const float* pb = pre0 + (long)b * T_STEPS * 64 + g;
    float pc = 0.0f, p1 = 0.0f, p2 = 0.0f;
    if (wv == 0) { pc = pb[0]; p1 = pb[64]; p2 = pb[128]; }

    float hs[16];
    #pragma unroll
    for (int k = 0; k < 16; ++k) hs[k] = 0.0f;
    float c = 0.0f;

    const int q4 = g >> 4;
    const float escale = (q4 == 2) ? -2.8853900817779268f : -1.4426950408889634f;
    const float am = (q4 == 2) ? 2.0f : 1.0f;
    const float aa = (q4 == 2) ? -1.0f : 0.0f;

    for (int tau = 0; tau < T_STEPS + 3; ++tau) {
        __syncthreads();
        const int t = tau - wv;
        if (t >= 0 && t < T_STEPS) {
            float xr[16];
            if (wv) {
                #pragma unroll
                for (int q = 0; q < 4; ++q)
                    *(float4*)&xr[q * 4] = *(const float4*)&buf[wv - 1][t][q * 4];
            }
            float r0 = fmaf(whh_r[0], hs[0], wv ? bg : pc);
            float r1 = whh_r[1] * hs[1];
            float r2 = whh_r[2] * hs[2];
            float r3 = whh_r[3] * hs[3];
            #pragma unroll
            for (int k = 4; k < 16; k += 4) {
                r0 = fmaf(whh_r[k + 0], hs[k + 0], r0);
                r1 = fmaf(whh_r[k + 1], hs[k + 1], r1);
                r2 = fmaf(whh_r[k + 2], hs[k + 2], r2);
                r3 = fmaf(whh_r[k + 3], hs[k + 3], r3);
            }
            float acc = (r0 + r1) + (r2 + r3);
            if (wv) {
                float p0 = wih_r[0] * xr[0];
                float q1 = wih_r[1] * xr[1];
                float q2 = wih_r[2] * xr[2];
                float q3 = wih_r[3] * xr[3];
                #pragma unroll
                for (int k = 4; k < 16; k += 4) {
                    p0 = fmaf(wih_r[k + 0], xr[k + 0], p0);
                    q1 = fmaf(wih_r[k + 1], xr[k + 1], q1);
                    q2 = fmaf(wih_r[k + 2], xr[k + 2], q2);
                    q3 = fmaf(wih_r[k + 3], xr[k + 3], q3);
                }
                acc += (p0 + q1) + (q2 + q3);
            }
            float e = EXP2F(escale * acc);
            float s = __builtin_amdgcn_rcpf(1.0f + e);
            float a = fmaf(am, s, aa);
#if HAVE_PERMLANE_SWAP
            unsigned au = __float_as_uint(a);
            uv2 r16 = __builtin_amdgcn_permlane16_swap(au, au, false, false);
            uv2 r32 = __builtin_amdgcn_permlane32_swap(au, au, false, false);
            unsigned fvu = sel16 ? r16[1] : r16[0];
            unsigned gvu = sel32 ? r32[1] : r32[0];
            uv2 r48 = __builtin_amdgcn_permlane16_swap(gvu, gvu, false, false);
            unsigned ovu = sel16 ? r48[1] : r48[0];
            float fv = __uint_as_float(fvu);
            float gv = __uint_as_float(gvu);
            float ov = __uint_as_float(ovu);
#else
            float fv = __shfl_xor(a, 16, 64);
            float gv = __shfl_xor(a, 32, 64);
            float ov = __shfl_xor(a, 48, 64);
#endif
            c = fmaf(fv, c, a * gv);
            float e2 = EXP2F(-2.8853900817779268f * c);
            float s2 = __builtin_amdgcn_rcpf(1.0f + e2);
            float hn = fmaf(ov + ov, s2, -ov);
            if (wv < 3 && g < 16) buf[wv][t][g] = hn;
            #pragma unroll
            for (int k = 0; k < 16; ++k) hs[k] = rl_f(hn, k);
            if (wv == 0) {
                pc = p1; p1 = p2;
                int tn = t + 3; tn = tn < T_STEPS ? tn : T_STEPS - 1;
                p2 = pb[(long)tn * 64];
            }
        }
    }

    if (wv == 3 && g < 16) {
        float a1 = b_fc1[g];
        #pragma unroll
        for (int k = 0; k < 16; ++k) a1 = fmaf(w_fc1[g * 16 + k], hs[k], a1);
        a1 = fmaxf(a1, 0.0f);
        float h1[16];
        #pragma unroll
        for (int k = 0; k < 16; ++k) h1[k] = rl_f(a1, k);
        float lg = -3.0e38f;
        if (g < 15) {
            lg = b_fc2[g];
            #pragma unroll
            for (int k = 0; k < 16; ++k) lg = fmaf(w_fc2[g * 16 + k], h1[k], lg);
        }
        float mx = lg;
        #pragma unroll
        for (int d = 8; d >= 1; d >>= 1) mx = fmaxf(mx, __shfl_xor(mx, d, 16));
        float ev = (g < 15) ? EXP2F(1.4426950408889634f * (lg - mx)) : 0.0f;
        float sm = ev;
        #pragma unroll
        for (int d = 8; d >= 1; d >>= 1) sm += __shfl_xor(sm, d, 16);
        if (g < 15) out[b * 15 + g] = ev * __builtin_amdgcn_rcpf(sm);
    }
}

extern "C" void kernel_launch(void* const* d_in, const int* in_sizes, int n_in,
                              void* d_out, int out_size, void* d_ws, size_t ws_size,
                              hipStream_t stream) {
    const float* x    = (const float*)d_in[0];
    const float* wih0 = (const float*)d_in[1];
    const float* whh0 = (const float*)d_in[2];
    const float* b0   = (const float*)d_in[3];
    const float* wih1 = (const float*)d_in[4];
    const float* whh1 = (const float*)d_in[5];
    const float* b1   = (const float*)d_in[6];
    const float* wih2 = (const float*)d_in[7];
    const float* whh2 = (const float*)d_in[8];
    const float* b2   = (const float*)d_in[9];
    const float* wih3 = (const float*)d_in[10];
    const float* whh3 = (const float*)d_in[11];
    const float* b3   = (const float*)d_in[12];
    const float* wfc1 = (const float*)d_in[13];
    const float* bfc1 = (const float*)d_in[14];
    const float* wfc2 = (const float*)d_in[15];
    const float* bfc2 = (const float*)d_in[16];

    float* pre0 = (float*)d_ws;                                       // 13,107,200 B
    unsigned short* Wh = (unsigned short*)((char*)d_ws + 13107200);   // 139,264 B
    unsigned short* Wl = (unsigned short*)((char*)d_ws + 13107200 + 139264);

    prepack_w<<<dim3((KTILES * 4 * 64 * 8 + 255) / 256), dim3(256), 0, stream>>>(wih0, Wh, Wl);
    pre0_gemm_v3<<<dim3(M_TOTAL / 64), dim3(256), 0, stream>>>(x, Wh, Wl, b0, pre0);
    mega_scan<<<dim3(256), dim3(256), 0, stream>>>(pre0, whh0,
        wih1, whh1, b1, wih2, whh2, b2, wih3, whh3, b3,
        wfc1, bfc1, wfc2, bfc2, (float*)d_out);
}